// Round 11
// baseline (1343.460 us; speedup 1.0000x reference)
//
#include <hip/hip_runtime.h>

#define N_NODES 100000
#define N_EDGES 3200000
#define HD      256
#define NGRAPH  128
#define NCLASS  10
#define BN_EPS  1e-5f
#define NBKT    782        // ceil(100000/128) dst buckets of 128 nodes
#define NBLK    256        // edge-chunk blocks (3.2M/256 = 12500 exact)
#define EPB     12500      // edges per block
#define AGG_NB  12500      // agg blocks (8 nodes each)

typedef unsigned short u16;
typedef unsigned int   u32;
typedef __attribute__((ext_vector_type(4))) float f32x4;
typedef __attribute__((ext_vector_type(8))) float f32x8;
typedef __attribute__((ext_vector_type(8))) short bf16x8;
typedef __attribute__((ext_vector_type(8))) u16   u16x8;
typedef __attribute__((ext_vector_type(4))) u16   u16x4;

__device__ __forceinline__ float b2f(u16 u){ return __uint_as_float(((unsigned)u) << 16); }
__device__ __forceinline__ u16 f2b(float f){
  unsigned x = __float_as_uint(f);
  x += 0x7fffu + ((x >> 16) & 1u);
  return (u16)(x >> 16);
}
__device__ __forceinline__ f32x4 c4(u16x4 v){
  f32x4 r = { b2f(v[0]), b2f(v[1]), b2f(v[2]), b2f(v[3]) };
  return r;
}
__device__ __forceinline__ f32x8 c8(u16x8 v){
  f32x8 r = { b2f(v[0]), b2f(v[1]), b2f(v[2]), b2f(v[3]),
              b2f(v[4]), b2f(v[5]), b2f(v[6]), b2f(v[7]) };
  return r;
}

// all 3 weight transposes in one launch (grid 768)
__global__ __launch_bounds__(256) void wt3_k(const float* __restrict__ W0, const float* __restrict__ W1,
                                             const float* __restrict__ W2, u16* __restrict__ Wt){
  int l = blockIdx.x >> 8;
  const float* W = (l == 0) ? W0 : (l == 1) ? W1 : W2;
  int i = (blockIdx.x & 255) * 256 + threadIdx.x;   // 65536 elements per layer
  int k = i >> 8, n = i & 255;
  Wt[(size_t)l * HD * HD + n * HD + k] = f2b(W[k * HD + n]);
}

// ---------------- CSR build via bucket counting-sort (no global atomics) ----------------
__global__ __launch_bounds__(256) void histA_k(const int* __restrict__ ei, u32* __restrict__ blkcnt){
  __shared__ u32 h[NBKT];
  int tid = threadIdx.x, blk = blockIdx.x;
  for (int j = tid; j < NBKT; j += 256) h[j] = 0;
  __syncthreads();
  const int* dst = ei + N_EDGES + blk * EPB;
  for (int i = tid; i < EPB; i += 256)
    atomicAdd(&h[((u32)dst[i]) >> 7], 1u);
  __syncthreads();
  for (int j = tid; j < NBKT; j += 256) blkcnt[blk * NBKT + j] = h[j];
}

__global__ __launch_bounds__(256) void scanB1_k(const u32* __restrict__ blkcnt, u32* __restrict__ offs_p,
                                                u32* __restrict__ total){
  __shared__ u32 sh[256];
  int b = blockIdx.x, tid = threadIdx.x;
  u32 v = blkcnt[tid * NBKT + b];
  sh[tid] = v;
  __syncthreads();
  #pragma unroll
  for (int o = 1; o < 256; o <<= 1){
    u32 t = (tid >= o) ? sh[tid - o] : 0u;
    __syncthreads();
    sh[tid] += t;
    __syncthreads();
  }
  offs_p[tid * NBKT + b] = sh[tid] - v;     // exclusive
  if (tid == 255) total[b] = sh[255];
}

__global__ __launch_bounds__(1024) void scanB2_k(const u32* __restrict__ total, u32* __restrict__ bkt_start){
  __shared__ u32 sh[1024];
  int tid = threadIdx.x;
  u32 v = (tid < NBKT) ? total[tid] : 0u;
  sh[tid] = v;
  __syncthreads();
  for (int o = 1; o < 1024; o <<= 1){
    u32 t = (tid >= o) ? sh[tid - o] : 0u;
    __syncthreads();
    sh[tid] += t;
    __syncthreads();
  }
  if (tid < NBKT) bkt_start[tid] = sh[tid] - v;
  if (tid == NBKT - 1) bkt_start[NBKT] = sh[tid];   // == N_EDGES
}

__global__ __launch_bounds__(256) void scatC_k(const int* __restrict__ ei, const u32* __restrict__ offs_p,
                                               const u32* __restrict__ bkt_start,
                                               int* __restrict__ esrc, int* __restrict__ edst){
  __shared__ u32 base[NBKT];
  int tid = threadIdx.x, blk = blockIdx.x;
  for (int j = tid; j < NBKT; j += 256)
    base[j] = bkt_start[j] + offs_p[blk * NBKT + j];
  __syncthreads();
  const int* src = ei + blk * EPB;
  const int* dst = ei + N_EDGES + blk * EPB;
  for (int i = tid; i < EPB; i += 256){
    int s = src[i], d = dst[i];
    u32 pos = atomicAdd(&base[((u32)d) >> 7], 1u);
    esrc[pos] = s;
    edst[pos] = d;
  }
}

__global__ __launch_bounds__(128) void csrD_k(const int* __restrict__ esrc, const int* __restrict__ edst,
                                              const u32* __restrict__ bkt_start, int* __restrict__ rowptr,
                                              float* __restrict__ dis, int* __restrict__ colx){
  __shared__ u32 cnt[128], sc[128], bas[128];
  int b = blockIdx.x, tid = threadIdx.x;
  int seg0 = (int)bkt_start[b], seg1 = (int)bkt_start[b + 1];
  cnt[tid] = 0;
  __syncthreads();
  for (int i = seg0 + tid; i < seg1; i += 128)
    atomicAdd(&cnt[edst[i] & 127], 1u);
  __syncthreads();
  u32 mycnt = cnt[tid];
  sc[tid] = mycnt;
  __syncthreads();
  #pragma unroll
  for (int o = 1; o < 128; o <<= 1){
    u32 t = (tid >= o) ? sc[tid - o] : 0u;
    __syncthreads();
    sc[tid] += t;
    __syncthreads();
  }
  u32 excl = sc[tid] - mycnt;
  int node = (b << 7) + tid;
  bas[tid] = seg0 + excl;
  if (node <= N_NODES) rowptr[node] = seg0 + (int)excl;        // node==N writes rowptr[N]=E
  if (node < N_NODES) dis[node] = rsqrtf((float)(mycnt + 1));  // in-degree + self-loop
  __syncthreads();
  cnt[tid] = 0;
  __syncthreads();
  for (int i = seg0 + tid; i < seg1; i += 128){
    int dl = edst[i] & 127;
    u32 p = atomicAdd(&cnt[dl], 1u);
    colx[bas[dl] + p] = esrc[i];
  }
}

// ---------------- GEMM: HN = (relu(X*a+b) @ W) * dis[row]  (A-resident, B reg-prefetch) ----------------
// layer 0: X is f32 (raw input), converted during staging (same f2b rounding as old cvt path)
// layers 1,2: X is bf16 outb, BN-affine+relu fused into staging

__device__ __forceinline__ int swzoff(int row, int kel){
  return (row * 512 + kel * 2) ^ ((row & 7) << 4);
}

__global__ __launch_bounds__(256) void gemm_k(const void* __restrict__ Xv, int xf32,
                                              const u16* __restrict__ Wt,
                                              const float* __restrict__ dis, const float* __restrict__ prm,
                                              int useprm, u16* __restrict__ HN)
{
  __shared__ u16x8 AsV[2048];   // 32 KB, byte-XOR-swizzled [64][256] bf16
  __shared__ u16x8 BsV[2048];
  char* As = (char*)AsV;
  char* Bs = (char*)BsV;
  int tid = threadIdx.x;
  int rowbase = blockIdx.x * 64;     // grid 1563; A staged ONCE, all 4 col-panels computed here
  int r = tid >> 2, q = tid & 3;
  {
    int grow = rowbase + r;
    #pragma unroll
    for (int j = 0; j < 8; ++j){
      u16x8 v = {0,0,0,0,0,0,0,0};
      if (grow < N_NODES){
        if (xf32){
          const float* src = (const float*)Xv + (size_t)grow * HD + q * 64 + j * 8;
          f32x4 f0 = *(const f32x4*)src;
          f32x4 f1 = *(const f32x4*)(src + 4);
          v[0]=f2b(f0[0]); v[1]=f2b(f0[1]); v[2]=f2b(f0[2]); v[3]=f2b(f0[3]);
          v[4]=f2b(f1[0]); v[5]=f2b(f1[1]); v[6]=f2b(f1[2]); v[7]=f2b(f1[3]);
        } else {
          v = *(const u16x8*)((const u16*)Xv + (size_t)grow * HD + q * 64 + j * 8);
          if (useprm){
            f32x8 a = *(const f32x8*)(prm + q * 64 + j * 8);
            f32x8 b = *(const f32x8*)(prm + HD + q * 64 + j * 8);
            f32x8 y = c8(v) * a + b;
            #pragma unroll
            for (int t = 0; t < 8; ++t) v[t] = f2b(fmaxf(y[t], 0.f));
          }
        }
      }
      *(u16x8*)(As + swzoff(r, q * 64 + j * 8)) = v;
    }
  }
  // prologue: panel 0 B -> LDS
  {
    const u16* wsrc = Wt + (size_t)r * HD + q * 64;
    #pragma unroll
    for (int j = 0; j < 8; ++j)
      *(u16x8*)(Bs + swzoff(r, q * 64 + j * 8)) = *(const u16x8*)(wsrc + j * 8);
  }
  __syncthreads();

  int w = tid >> 6, lane = tid & 63;
  int wm = w >> 1, wn = w & 1;
  int lr = lane & 15, lg = lane >> 4;

  u16x8 bR[8];    // next-panel register prefetch

  #pragma unroll 1
  for (int panel = 0; panel < 4; ++panel){
    int colbase = panel * 64;
    if (panel < 3){
      const u16* wsrc = Wt + (size_t)(colbase + 64 + r) * HD + q * 64;
      #pragma unroll
      for (int j = 0; j < 8; ++j) bR[j] = *(const u16x8*)(wsrc + j * 8);
    }

    f32x4 acc00 = {0,0,0,0}, acc01 = {0,0,0,0}, acc10 = {0,0,0,0}, acc11 = {0,0,0,0};
    #pragma unroll
    for (int ks = 0; ks < 8; ++ks){
      int ka = ks * 32 + lg * 8;
      bf16x8 a0 = *(const bf16x8*)(As + swzoff(wm * 32 + lr,      ka));
      bf16x8 a1 = *(const bf16x8*)(As + swzoff(wm * 32 + 16 + lr, ka));
      bf16x8 b0 = *(const bf16x8*)(Bs + swzoff(wn * 32 + lr,      ka));
      bf16x8 b1 = *(const bf16x8*)(Bs + swzoff(wn * 32 + 16 + lr, ka));
      acc00 = __builtin_amdgcn_mfma_f32_16x16x32_bf16(a0, b0, acc00, 0, 0, 0);
      acc01 = __builtin_amdgcn_mfma_f32_16x16x32_bf16(a0, b1, acc01, 0, 0, 0);
      acc10 = __builtin_amdgcn_mfma_f32_16x16x32_bf16(a1, b0, acc10, 0, 0, 0);
      acc11 = __builtin_amdgcn_mfma_f32_16x16x32_bf16(a1, b1, acc11, 0, 0, 0);
    }

    // C/D layout: col = lane&15, row = (lane>>4)*4 + reg  [measured m89]
    #pragma unroll
    for (int mt = 0; mt < 2; ++mt){
      f32x4 ac0 = mt ? acc10 : acc00;
      f32x4 ac1 = mt ? acc11 : acc01;
      #pragma unroll
      for (int rr = 0; rr < 4; ++rr){
        int grow = rowbase + wm * 32 + mt * 16 + lg * 4 + rr;
        if (grow < N_NODES){
          float dd = dis[grow];
          size_t base = (size_t)grow * HD + colbase + wn * 32 + lr;
          HN[base]      = f2b(ac0[rr] * dd);
          HN[base + 16] = f2b(ac1[rr] * dd);
        }
      }
    }
    __syncthreads();                   // all waves done READING Bs
    if (panel < 3){
      #pragma unroll
      for (int j = 0; j < 8; ++j)
        *(u16x8*)(Bs + swzoff(r, q * 64 + j * 8)) = bR[j];
    }
    __syncthreads();                   // Bs ready for next panel
  }
}

// ---------------- aggregation + fused BN partial stats ----------------
// OUTB[d] = bf16( dis[d]*(sum_{edges} HN[s] + HN[d]) ); per-block 512 partials (sum,sumsq)
// computed from the in-register f32 results (pre-rounding -> closer to reference stats).

__global__ __launch_bounds__(256) void agg_k(const u16* __restrict__ HN, const int* __restrict__ rowptr,
                                             const int* __restrict__ colx, const float* __restrict__ dis,
                                             u16* __restrict__ OUTB, float* __restrict__ part)
{
  __shared__ float red[8][512];   // 16 KB
  int wid = threadIdx.x >> 6, lane = threadIdx.x & 63;
  int node = blockIdx.x * 8 + wid * 2 + (lane >> 5);   // grid 12500*8 = 100000 exact
  int c0 = (lane & 31) * 8;                             // 8 cols (16B) per lane
  const u16* base = HN + (size_t)c0;

  f32x8 a0 = {0,0,0,0,0,0,0,0}, a1 = a0, a2 = a0, a3 = a0;
  int e = rowptr[node], end = rowptr[node + 1];
  for (; e + 4 <= end; e += 4){
    int s0 = colx[e], s1 = colx[e + 1], s2 = colx[e + 2], s3 = colx[e + 3];
    u16x8 v0 = *(const u16x8*)(base + (size_t)s0 * HD);
    u16x8 v1 = *(const u16x8*)(base + (size_t)s1 * HD);
    u16x8 v2 = *(const u16x8*)(base + (size_t)s2 * HD);
    u16x8 v3 = *(const u16x8*)(base + (size_t)s3 * HD);
    a0 += c8(v0); a1 += c8(v1); a2 += c8(v2); a3 += c8(v3);
  }
  for (; e < end; ++e)
    a0 += c8(*(const u16x8*)(base + (size_t)colx[e] * HD));
  a0 += c8(*(const u16x8*)(base + (size_t)node * HD));   // self-loop
  f32x8 res = ((a0 + a1) + (a2 + a3)) * dis[node];
  u16x8 o = { f2b(res[0]), f2b(res[1]), f2b(res[2]), f2b(res[3]),
              f2b(res[4]), f2b(res[5]), f2b(res[6]), f2b(res[7]) };
  *(u16x8*)(OUTB + (size_t)node * HD + c0) = o;

  // fused stat1: 8 groups (wave x node-half) x 512 slots
  int grp = wid * 2 + (lane >> 5);
  #pragma unroll
  for (int t = 0; t < 8; ++t){
    red[grp][c0 + t] = res[t];
    red[grp][256 + c0 + t] = res[t] * res[t];
  }
  __syncthreads();
  for (int slot = threadIdx.x; slot < 512; slot += 256){
    float t = 0.f;
    #pragma unroll
    for (int g = 0; g < 8; ++g) t += red[g][slot];
    part[(size_t)blockIdx.x * 512 + slot] = t;
  }
}

// fused stage2+prep over 12500 block-partials
__global__ __launch_bounds__(256) void stat2p_k(const float* __restrict__ part,
                                                const float* __restrict__ gamma,
                                                const float* __restrict__ beta,
                                                float* __restrict__ prm, int nblk){
  __shared__ float shs[256], shq[256];
  int c = blockIdx.x, tid = threadIdx.x;
  float s = 0.f, q = 0.f;
  for (int b = tid; b < nblk; b += 256){
    s += part[(size_t)b * 512 + c];
    q += part[(size_t)b * 512 + 256 + c];
  }
  shs[tid] = s; shq[tid] = q;
  __syncthreads();
  #pragma unroll
  for (int o = 128; o > 0; o >>= 1){
    if (tid < o){ shs[tid] += shs[tid + o]; shq[tid] += shq[tid + o]; }
    __syncthreads();
  }
  if (tid == 0){
    float mean = shs[0] / (float)N_NODES;
    float var  = fmaxf(shq[0] / (float)N_NODES - mean * mean, 0.f);
    float inv  = rsqrtf(var + BN_EPS);
    float a = gamma[c] * inv;
    prm[c] = a;
    prm[HD + c] = beta[c] - mean * a;
  }
}

// ---------------- pooling + MLP head ----------------

__global__ __launch_bounds__(256) void bnd2_k(const int* __restrict__ batch, int* __restrict__ gs,
                                              int* __restrict__ ge){
  int i = blockIdx.x * 256 + threadIdx.x;
  if (i >= N_NODES) return;
  int b = batch[i];
  if (i == 0) gs[b] = 0;
  else {
    int p = batch[i - 1];
    if (p != b){ ge[p] = i; gs[b] = i; }
  }
  if (i == N_NODES - 1) ge[b] = N_NODES;
}

// pool with layer-2 BN affine + relu fused (reads raw outb)
__global__ __launch_bounds__(256) void pool_k(const u16* __restrict__ outb, const float* __restrict__ prm,
                                              const int* __restrict__ gs, const int* __restrict__ ge,
                                              float* __restrict__ pooled){
  __shared__ float red[4][HD];
  int g = blockIdx.x;
  int s = gs[g], e = ge[g];
  int w = threadIdx.x >> 6;
  int c0 = (threadIdx.x & 63) * 4;
  f32x4 pa = *(const f32x4*)(prm + c0);
  f32x4 pb = *(const f32x4*)(prm + HD + c0);
  f32x4 acc = {0,0,0,0};
  for (int r = s + w; r < e; r += 4){
    f32x4 v = c4(*(const u16x4*)(outb + (size_t)r * HD + c0));
    f32x4 y = v * pa + pb;
    y[0] = fmaxf(y[0], 0.f); y[1] = fmaxf(y[1], 0.f);
    y[2] = fmaxf(y[2], 0.f); y[3] = fmaxf(y[3], 0.f);
    acc += y;
  }
  *(f32x4*)&red[w][c0] = acc;
  __syncthreads();
  if (w == 0){
    f32x4 t = *(f32x4*)&red[0][c0];
    t += *(f32x4*)&red[1][c0];
    t += *(f32x4*)&red[2][c0];
    t += *(f32x4*)&red[3][c0];
    float cntf = (e > s) ? (float)(e - s) : 1.0f;
    *(f32x4*)(pooled + g * HD + c0) = t * (1.0f / cntf);
  }
}

__global__ __launch_bounds__(256) void lin1_k(const float* __restrict__ pooled, const float* __restrict__ w,
                                              const float* __restrict__ b, float* __restrict__ z1){
  __shared__ float pr[HD];
  int g = blockIdx.x, c = threadIdx.x;
  pr[c] = pooled[g * HD + c];
  __syncthreads();
  float acc = b[c];
  #pragma unroll 8
  for (int k = 0; k < HD; ++k) acc = fmaf(pr[k], w[k * HD + c], acc);
  z1[g * HD + c] = acc;
}

__global__ __launch_bounds__(256) void bn1_k(float* __restrict__ z1, const float* __restrict__ g,
                                             const float* __restrict__ b){
  int c = threadIdx.x;
  float s = 0.f, q = 0.f;
  for (int r = 0; r < NGRAPH; ++r){
    float v = z1[r * HD + c];
    s += v; q += v * v;
  }
  float mean = s / (float)NGRAPH;
  float var  = fmaxf(q / (float)NGRAPH - mean * mean, 0.f);
  float inv  = rsqrtf(var + BN_EPS);
  float a = g[c] * inv, sh = b[c] - mean * a;
  for (int r = 0; r < NGRAPH; ++r)
    z1[r * HD + c] = fmaxf(z1[r * HD + c] * a + sh, 0.f);
}

__global__ __launch_bounds__(256) void lin2_k(const float* __restrict__ z1, const float* __restrict__ w,
                                              const float* __restrict__ b, float* __restrict__ out){
  __shared__ float zr[HD];
  int g = blockIdx.x;
  zr[threadIdx.x] = z1[g * HD + threadIdx.x];
  __syncthreads();
  if (threadIdx.x < NCLASS){
    float acc = b[threadIdx.x];
    #pragma unroll 8
    for (int k = 0; k < HD; ++k) acc = fmaf(zr[k], w[k * NCLASS + threadIdx.x], acc);
    out[g * NCLASS + threadIdx.x] = acc;
  }
}

// ---------------- host launch ----------------

extern "C" void kernel_launch(void* const* d_in, const int* in_sizes, int n_in,
                              void* d_out, int out_size, void* d_ws, size_t ws_size,
                              hipStream_t stream)
{
  const float* x      = (const float*)d_in[0];
  const int*   ei     = (const int*)d_in[1];
  const int*   batch  = (const int*)d_in[2];
  const float* W[3]   = {(const float*)d_in[3], (const float*)d_in[7], (const float*)d_in[11]};
  const float* gam[3] = {(const float*)d_in[5], (const float*)d_in[9], (const float*)d_in[13]};
  const float* bet[3] = {(const float*)d_in[6], (const float*)d_in[10], (const float*)d_in[14]};
  const float* lin1_w = (const float*)d_in[15];
  const float* lin1_b = (const float*)d_in[16];
  const float* bn1_g  = (const float*)d_in[17];
  const float* bn1_b  = (const float*)d_in[18];
  const float* lin2_w = (const float*)d_in[19];
  const float* lin2_b = (const float*)d_in[20];
  float* out = (float*)d_out;

  char* ws = (char*)d_ws;
  size_t off = 0;
  auto alloc = [&](size_t bytes) -> void* {
    void* p = ws + off;
    off = (off + bytes + 255) & ~(size_t)255;
    return p;
  };
  u16*   hn     = (u16*)alloc((size_t)N_NODES * HD * 2);     // 51.2 MB
  u16*   outb   = (u16*)alloc((size_t)N_NODES * HD * 2);     // 51.2 MB
  u16*   wt     = (u16*)alloc((size_t)3 * HD * HD * 2);
  int*   rowptr = (int*)alloc((size_t)(N_NODES + 1) * 4);
  int*   colx   = (int*)alloc((size_t)N_EDGES * 4);
  float* dis    = (float*)alloc((size_t)N_NODES * 4);
  float* prm    = (float*)alloc(2 * HD * 4);
  float* part   = (float*)alloc((size_t)AGG_NB * 512 * 4);   // 25.6 MB
  int*   gs     = (int*)alloc(NGRAPH * 4);
  int*   ge     = (int*)alloc(NGRAPH * 4);
  float* pooled = (float*)alloc((size_t)NGRAPH * HD * 4);
  float* z1     = (float*)alloc((size_t)NGRAPH * HD * 4);
  (void)ws_size; (void)n_in; (void)in_sizes; (void)out_size;

  // build-phase scratch aliases outb (overwritten later by agg_k) and hn (written by gemm_k).
  int* esrc      = (int*)outb;                        // bytes [0, 12.8 MB)
  int* edst      = esrc + (size_t)N_EDGES;            // bytes [12.8, 25.6 MB)
  u32* blkcnt    = (u32*)(edst + (size_t)N_EDGES);    // bytes [25.6, 26.4 MB)
  u32* offs_p    = blkcnt + (size_t)NBLK * NBKT;      // bytes [26.4, 27.2 MB)  < 51.2 MB
  u32* total     = (u32*)hn;                          // 3.1 KB (read before gemm_k writes hn)
  u32* bkt_start = (u32*)hn + 1024;                   // 3.1 KB

  const int NB1 = (N_NODES + 255) / 256;            // 391

  wt3_k<<<768, 256, 0, stream>>>(W[0], W[1], W[2], wt);

  // CSR build: bucket counting-sort (no global atomics, locality-preserving writes)
  histA_k <<<NBLK, 256, 0, stream>>>(ei, blkcnt);
  scanB1_k<<<NBKT, 256, 0, stream>>>(blkcnt, offs_p, total);
  scanB2_k<<<1, 1024, 0, stream>>>(total, bkt_start);
  scatC_k <<<NBLK, 256, 0, stream>>>(ei, offs_p, bkt_start, esrc, edst);
  csrD_k  <<<NBKT, 128, 0, stream>>>(esrc, edst, bkt_start, rowptr, dis, colx);

  for (int l = 0; l < 3; ++l){
    const void* gin = (l == 0) ? (const void*)x : (const void*)outb;
    gemm_k<<<1563, 256, 0, stream>>>(gin, l == 0, wt + (size_t)l * HD * HD, dis, prm, l > 0, hn);
    agg_k<<<AGG_NB, 256, 0, stream>>>(hn, rowptr, colx, dis, outb, part);
    stat2p_k<<<256, 256, 0, stream>>>(part, gam[l], bet[l], prm, AGG_NB);
  }

  hipMemsetAsync(gs, 0x7f, NGRAPH * 4, stream);
  hipMemsetAsync(ge, 0, NGRAPH * 4, stream);
  bnd2_k<<<NB1, 256, 0, stream>>>(batch, gs, ge);
  pool_k<<<NGRAPH, 256, 0, stream>>>(outb, prm, gs, ge, pooled);
  lin1_k<<<NGRAPH, 256, 0, stream>>>(pooled, lin1_w, lin1_b, z1);
  bn1_k<<<1, 256, 0, stream>>>(z1, bn1_g, bn1_b);
  lin2_k<<<NGRAPH, 256, 0, stream>>>(z1, lin2_w, lin2_b, out);
}

// Round 12
// 1256.627 us; speedup vs baseline: 1.0691x; 1.0691x over previous
//
#include <hip/hip_runtime.h>

#define N_NODES 100000
#define N_EDGES 3200000
#define HD      256
#define NGRAPH  128
#define NCLASS  10
#define BN_EPS  1e-5f
#define NBKT    782        // ceil(100000/128) dst buckets of 128 nodes
#define NBLK    256        // edge-chunk blocks (3.2M/256 = 12500 exact)
#define EPB     12500      // edges per block

typedef unsigned short u16;
typedef unsigned int   u32;
typedef __attribute__((ext_vector_type(4))) float f32x4;
typedef __attribute__((ext_vector_type(8))) float f32x8;
typedef __attribute__((ext_vector_type(8))) short bf16x8;
typedef __attribute__((ext_vector_type(8))) u16   u16x8;
typedef __attribute__((ext_vector_type(4))) u16   u16x4;

__device__ __forceinline__ float b2f(u16 u){ return __uint_as_float(((unsigned)u) << 16); }
__device__ __forceinline__ u16 f2b(float f){
  unsigned x = __float_as_uint(f);
  x += 0x7fffu + ((x >> 16) & 1u);
  return (u16)(x >> 16);
}
__device__ __forceinline__ f32x4 c4(u16x4 v){
  f32x4 r = { b2f(v[0]), b2f(v[1]), b2f(v[2]), b2f(v[3]) };
  return r;
}
__device__ __forceinline__ f32x8 c8(u16x8 v){
  f32x8 r = { b2f(v[0]), b2f(v[1]), b2f(v[2]), b2f(v[3]),
              b2f(v[4]), b2f(v[5]), b2f(v[6]), b2f(v[7]) };
  return r;
}

// ---------------- conversion / preprocessing ----------------

__global__ __launch_bounds__(256) void cvt_k(const float* __restrict__ x, u16* __restrict__ xb){
  size_t i = ((size_t)blockIdx.x * 256 + threadIdx.x) * 8;
  f32x4 v0 = *(const f32x4*)(x + i);
  f32x4 v1 = *(const f32x4*)(x + i + 4);
  u16x8 o = { f2b(v0[0]), f2b(v0[1]), f2b(v0[2]), f2b(v0[3]),
              f2b(v1[0]), f2b(v1[1]), f2b(v1[2]), f2b(v1[3]) };
  *(u16x8*)(xb + i) = o;
}

// all 3 weight transposes in one launch (grid 768)
__global__ __launch_bounds__(256) void wt3_k(const float* __restrict__ W0, const float* __restrict__ W1,
                                             const float* __restrict__ W2, u16* __restrict__ Wt){
  int l = blockIdx.x >> 8;
  const float* W = (l == 0) ? W0 : (l == 1) ? W1 : W2;
  int i = (blockIdx.x & 255) * 256 + threadIdx.x;   // 65536 elements per layer
  int k = i >> 8, n = i & 255;
  Wt[(size_t)l * HD * HD + n * HD + k] = f2b(W[k * HD + n]);
}

// ---------------- CSR build via bucket counting-sort (no global atomics) ----------------
__global__ __launch_bounds__(256) void histA_k(const int* __restrict__ ei, u32* __restrict__ blkcnt){
  __shared__ u32 h[NBKT];
  int tid = threadIdx.x, blk = blockIdx.x;
  for (int j = tid; j < NBKT; j += 256) h[j] = 0;
  __syncthreads();
  const int* dst = ei + N_EDGES + blk * EPB;
  for (int i = tid; i < EPB; i += 256)
    atomicAdd(&h[((u32)dst[i]) >> 7], 1u);
  __syncthreads();
  for (int j = tid; j < NBKT; j += 256) blkcnt[blk * NBKT + j] = h[j];
}

__global__ __launch_bounds__(256) void scanB1_k(const u32* __restrict__ blkcnt, u32* __restrict__ offs_p,
                                                u32* __restrict__ total){
  __shared__ u32 sh[256];
  int b = blockIdx.x, tid = threadIdx.x;
  u32 v = blkcnt[tid * NBKT + b];
  sh[tid] = v;
  __syncthreads();
  #pragma unroll
  for (int o = 1; o < 256; o <<= 1){
    u32 t = (tid >= o) ? sh[tid - o] : 0u;
    __syncthreads();
    sh[tid] += t;
    __syncthreads();
  }
  offs_p[tid * NBKT + b] = sh[tid] - v;     // exclusive
  if (tid == 255) total[b] = sh[255];
}

__global__ __launch_bounds__(1024) void scanB2_k(const u32* __restrict__ total, u32* __restrict__ bkt_start){
  __shared__ u32 sh[1024];
  int tid = threadIdx.x;
  u32 v = (tid < NBKT) ? total[tid] : 0u;
  sh[tid] = v;
  __syncthreads();
  for (int o = 1; o < 1024; o <<= 1){
    u32 t = (tid >= o) ? sh[tid - o] : 0u;
    __syncthreads();
    sh[tid] += t;
    __syncthreads();
  }
  if (tid < NBKT) bkt_start[tid] = sh[tid] - v;
  if (tid == NBKT - 1) bkt_start[NBKT] = sh[tid];   // == N_EDGES
}

__global__ __launch_bounds__(256) void scatC_k(const int* __restrict__ ei, const u32* __restrict__ offs_p,
                                               const u32* __restrict__ bkt_start,
                                               int* __restrict__ esrc, int* __restrict__ edst){
  __shared__ u32 base[NBKT];
  int tid = threadIdx.x, blk = blockIdx.x;
  for (int j = tid; j < NBKT; j += 256)
    base[j] = bkt_start[j] + offs_p[blk * NBKT + j];
  __syncthreads();
  const int* src = ei + blk * EPB;
  const int* dst = ei + N_EDGES + blk * EPB;
  for (int i = tid; i < EPB; i += 256){
    int s = src[i], d = dst[i];
    u32 pos = atomicAdd(&base[((u32)d) >> 7], 1u);
    esrc[pos] = s;
    edst[pos] = d;
  }
}

__global__ __launch_bounds__(128) void csrD_k(const int* __restrict__ esrc, const int* __restrict__ edst,
                                              const u32* __restrict__ bkt_start, int* __restrict__ rowptr,
                                              float* __restrict__ dis, int* __restrict__ colx){
  __shared__ u32 cnt[128], sc[128], bas[128];
  int b = blockIdx.x, tid = threadIdx.x;
  int seg0 = (int)bkt_start[b], seg1 = (int)bkt_start[b + 1];
  cnt[tid] = 0;
  __syncthreads();
  for (int i = seg0 + tid; i < seg1; i += 128)
    atomicAdd(&cnt[edst[i] & 127], 1u);
  __syncthreads();
  u32 mycnt = cnt[tid];
  sc[tid] = mycnt;
  __syncthreads();
  #pragma unroll
  for (int o = 1; o < 128; o <<= 1){
    u32 t = (tid >= o) ? sc[tid - o] : 0u;
    __syncthreads();
    sc[tid] += t;
    __syncthreads();
  }
  u32 excl = sc[tid] - mycnt;
  int node = (b << 7) + tid;
  bas[tid] = seg0 + excl;
  if (node <= N_NODES) rowptr[node] = seg0 + (int)excl;        // node==N writes rowptr[N]=E
  if (node < N_NODES) dis[node] = rsqrtf((float)(mycnt + 1));  // in-degree + self-loop
  __syncthreads();
  cnt[tid] = 0;
  __syncthreads();
  for (int i = seg0 + tid; i < seg1; i += 128){
    int dl = edst[i] & 127;
    u32 p = atomicAdd(&cnt[dl], 1u);
    colx[bas[dl] + p] = esrc[i];
  }
}

// ---------------- GEMM: HN = (relu(X*a+b) @ W) * dis[row]  (A-resident, B reg-prefetch) ----------------

__device__ __forceinline__ int swzoff(int row, int kel){
  return (row * 512 + kel * 2) ^ ((row & 7) << 4);
}

__global__ __launch_bounds__(256) void gemm_k(const u16* __restrict__ X, const u16* __restrict__ Wt,
                                              const float* __restrict__ dis, const float* __restrict__ prm,
                                              int useprm, u16* __restrict__ HN)
{
  __shared__ u16x8 AsV[2048];   // 32 KB, byte-XOR-swizzled [64][256] bf16
  __shared__ u16x8 BsV[2048];
  char* As = (char*)AsV;
  char* Bs = (char*)BsV;
  int tid = threadIdx.x;
  int rowbase = blockIdx.x * 64;     // grid 1563; A staged ONCE, all 4 col-panels computed here
  int r = tid >> 2, q = tid & 3;
  {
    int grow = rowbase + r;
    const u16* src = X + (size_t)grow * HD + q * 64;
    #pragma unroll
    for (int j = 0; j < 8; ++j){
      u16x8 v = {0,0,0,0,0,0,0,0};
      if (grow < N_NODES) v = *(const u16x8*)(src + j * 8);
      if (useprm){
        f32x8 a = *(const f32x8*)(prm + q * 64 + j * 8);
        f32x8 b = *(const f32x8*)(prm + HD + q * 64 + j * 8);
        f32x8 y = c8(v) * a + b;
        #pragma unroll
        for (int t = 0; t < 8; ++t) v[t] = f2b(fmaxf(y[t], 0.f));
      }
      *(u16x8*)(As + swzoff(r, q * 64 + j * 8)) = v;
    }
  }
  // prologue: panel 0 B -> LDS
  {
    const u16* wsrc = Wt + (size_t)r * HD + q * 64;
    #pragma unroll
    for (int j = 0; j < 8; ++j)
      *(u16x8*)(Bs + swzoff(r, q * 64 + j * 8)) = *(const u16x8*)(wsrc + j * 8);
  }
  __syncthreads();

  int w = tid >> 6, lane = tid & 63;
  int wm = w >> 1, wn = w & 1;
  int lr = lane & 15, lg = lane >> 4;

  u16x8 bR[8];    // next-panel register prefetch (T14 async-stage)

  #pragma unroll 1
  for (int panel = 0; panel < 4; ++panel){
    int colbase = panel * 64;
    if (panel < 3){
      const u16* wsrc = Wt + (size_t)(colbase + 64 + r) * HD + q * 64;
      #pragma unroll
      for (int j = 0; j < 8; ++j) bR[j] = *(const u16x8*)(wsrc + j * 8);   // loads in flight over MFMA
    }

    f32x4 acc00 = {0,0,0,0}, acc01 = {0,0,0,0}, acc10 = {0,0,0,0}, acc11 = {0,0,0,0};
    #pragma unroll
    for (int ks = 0; ks < 8; ++ks){
      int ka = ks * 32 + lg * 8;
      bf16x8 a0 = *(const bf16x8*)(As + swzoff(wm * 32 + lr,      ka));
      bf16x8 a1 = *(const bf16x8*)(As + swzoff(wm * 32 + 16 + lr, ka));
      bf16x8 b0 = *(const bf16x8*)(Bs + swzoff(wn * 32 + lr,      ka));
      bf16x8 b1 = *(const bf16x8*)(Bs + swzoff(wn * 32 + 16 + lr, ka));
      acc00 = __builtin_amdgcn_mfma_f32_16x16x32_bf16(a0, b0, acc00, 0, 0, 0);
      acc01 = __builtin_amdgcn_mfma_f32_16x16x32_bf16(a0, b1, acc01, 0, 0, 0);
      acc10 = __builtin_amdgcn_mfma_f32_16x16x32_bf16(a1, b0, acc10, 0, 0, 0);
      acc11 = __builtin_amdgcn_mfma_f32_16x16x32_bf16(a1, b1, acc11, 0, 0, 0);
    }

    // epilogue store for this panel (overlaps with bR loads still in flight)
    // C/D layout: col = lane&15, row = (lane>>4)*4 + reg  [measured m89]
    #pragma unroll
    for (int mt = 0; mt < 2; ++mt){
      f32x4 ac0 = mt ? acc10 : acc00;
      f32x4 ac1 = mt ? acc11 : acc01;
      #pragma unroll
      for (int rr = 0; rr < 4; ++rr){
        int grow = rowbase + wm * 32 + mt * 16 + lg * 4 + rr;
        if (grow < N_NODES){
          float dd = dis[grow];
          size_t base = (size_t)grow * HD + colbase + wn * 32 + lr;
          HN[base]      = f2b(ac0[rr] * dd);
          HN[base + 16] = f2b(ac1[rr] * dd);
        }
      }
    }
    __syncthreads();                   // all waves done READING Bs
    if (panel < 3){
      #pragma unroll
      for (int j = 0; j < 8; ++j)
        *(u16x8*)(Bs + swzoff(r, q * 64 + j * 8)) = bR[j];
    }
    __syncthreads();                   // Bs ready for next panel
  }
}

// ---------------- aggregation: OUTB[d] = bf16( dis[d]*(sum_{edges} HN[s] + HN[d]) ) ----------------
// R4 form (proven 222us): 2 nodes/wave, 4-deep unroll, full 512B row per gather.

__global__ __launch_bounds__(256) void agg_k(const u16* __restrict__ HN, const int* __restrict__ rowptr,
                                             const int* __restrict__ colx, const float* __restrict__ dis,
                                             u16* __restrict__ OUTB)
{
  int wid = threadIdx.x >> 6, lane = threadIdx.x & 63;
  int node = blockIdx.x * 8 + wid * 2 + (lane >> 5);   // grid 12500*8 = 100000 exact
  int c0 = (lane & 31) * 8;                             // 8 cols (16B) per lane
  const u16* base = HN + (size_t)c0;

  f32x8 a0 = {0,0,0,0,0,0,0,0}, a1 = a0, a2 = a0, a3 = a0;
  int e = rowptr[node], end = rowptr[node + 1];
  for (; e + 4 <= end; e += 4){
    int s0 = colx[e], s1 = colx[e + 1], s2 = colx[e + 2], s3 = colx[e + 3];
    u16x8 v0 = *(const u16x8*)(base + (size_t)s0 * HD);
    u16x8 v1 = *(const u16x8*)(base + (size_t)s1 * HD);
    u16x8 v2 = *(const u16x8*)(base + (size_t)s2 * HD);
    u16x8 v3 = *(const u16x8*)(base + (size_t)s3 * HD);
    a0 += c8(v0); a1 += c8(v1); a2 += c8(v2); a3 += c8(v3);
  }
  for (; e < end; ++e)
    a0 += c8(*(const u16x8*)(base + (size_t)colx[e] * HD));
  a0 += c8(*(const u16x8*)(base + (size_t)node * HD));   // self-loop
  f32x8 res = ((a0 + a1) + (a2 + a3)) * dis[node];
  u16x8 o = { f2b(res[0]), f2b(res[1]), f2b(res[2]), f2b(res[3]),
              f2b(res[4]), f2b(res[5]), f2b(res[6]), f2b(res[7]) };
  *(u16x8*)(OUTB + (size_t)node * HD + c0) = o;
}

// ---------------- batch-norm stats: two-stage, both stages parallel ----------------

__global__ __launch_bounds__(256) void stat1_k(const u16* __restrict__ OUTB, float* __restrict__ part){
  __shared__ float red[8][512];
  int tid = threadIdx.x;
  int c0 = (tid & 31) * 8;
  int rg = tid >> 5;
  f32x8 s = {0,0,0,0,0,0,0,0}, q = s;
  for (int r = blockIdx.x * 8 + rg; r < N_NODES; r += gridDim.x * 8){
    f32x8 v = c8(*(const u16x8*)(OUTB + (size_t)r * HD + c0));
    s += v; q += v * v;
  }
  #pragma unroll
  for (int e = 0; e < 8; ++e){
    red[rg][c0 + e] = s[e];
    red[rg][256 + c0 + e] = q[e];
  }
  __syncthreads();
  for (int slot = tid; slot < 512; slot += 256){
    float t = 0.f;
    #pragma unroll
    for (int g = 0; g < 8; ++g) t += red[g][slot];
    part[(size_t)blockIdx.x * 512 + slot] = t;
  }
}

// fused stage2+prep: block c reduces slots c (sum) and c+256 (sumsq) over 1024 partials,
// then computes the BN affine params directly.
__global__ __launch_bounds__(256) void stat2p_k(const float* __restrict__ part,
                                                const float* __restrict__ gamma,
                                                const float* __restrict__ beta,
                                                float* __restrict__ prm, int nblk){
  __shared__ float shs[256], shq[256];
  int c = blockIdx.x, tid = threadIdx.x;
  float s = 0.f, q = 0.f;
  for (int b = tid; b < nblk; b += 256){
    s += part[(size_t)b * 512 + c];
    q += part[(size_t)b * 512 + 256 + c];
  }
  shs[tid] = s; shq[tid] = q;
  __syncthreads();
  #pragma unroll
  for (int o = 128; o > 0; o >>= 1){
    if (tid < o){ shs[tid] += shs[tid + o]; shq[tid] += shq[tid + o]; }
    __syncthreads();
  }
  if (tid == 0){
    float mean = shs[0] / (float)N_NODES;
    float var  = fmaxf(shq[0] / (float)N_NODES - mean * mean, 0.f);
    float inv  = rsqrtf(var + BN_EPS);
    float a = gamma[c] * inv;
    prm[c] = a;
    prm[HD + c] = beta[c] - mean * a;
  }
}

// ---------------- pooling + MLP head ----------------

__global__ __launch_bounds__(256) void bnd2_k(const int* __restrict__ batch, int* __restrict__ gs,
                                              int* __restrict__ ge){
  int i = blockIdx.x * 256 + threadIdx.x;
  if (i >= N_NODES) return;
  int b = batch[i];
  if (i == 0) gs[b] = 0;
  else {
    int p = batch[i - 1];
    if (p != b){ ge[p] = i; gs[b] = i; }
  }
  if (i == N_NODES - 1) ge[b] = N_NODES;
}

// pool with layer-2 BN affine + relu fused (reads raw outb)
__global__ __launch_bounds__(256) void pool_k(const u16* __restrict__ outb, const float* __restrict__ prm,
                                              const int* __restrict__ gs, const int* __restrict__ ge,
                                              float* __restrict__ pooled){
  __shared__ float red[4][HD];
  int g = blockIdx.x;
  int s = gs[g], e = ge[g];
  int w = threadIdx.x >> 6;
  int c0 = (threadIdx.x & 63) * 4;
  f32x4 pa = *(const f32x4*)(prm + c0);
  f32x4 pb = *(const f32x4*)(prm + HD + c0);
  f32x4 acc = {0,0,0,0};
  for (int r = s + w; r < e; r += 4){
    f32x4 v = c4(*(const u16x4*)(outb + (size_t)r * HD + c0));
    f32x4 y = v * pa + pb;
    y[0] = fmaxf(y[0], 0.f); y[1] = fmaxf(y[1], 0.f);
    y[2] = fmaxf(y[2], 0.f); y[3] = fmaxf(y[3], 0.f);
    acc += y;
  }
  *(f32x4*)&red[w][c0] = acc;
  __syncthreads();
  if (w == 0){
    f32x4 t = *(f32x4*)&red[0][c0];
    t += *(f32x4*)&red[1][c0];
    t += *(f32x4*)&red[2][c0];
    t += *(f32x4*)&red[3][c0];
    float cntf = (e > s) ? (float)(e - s) : 1.0f;
    *(f32x4*)(pooled + g * HD + c0) = t * (1.0f / cntf);
  }
}

__global__ __launch_bounds__(256) void lin1_k(const float* __restrict__ pooled, const float* __restrict__ w,
                                              const float* __restrict__ b, float* __restrict__ z1){
  __shared__ float pr[HD];
  int g = blockIdx.x, c = threadIdx.x;
  pr[c] = pooled[g * HD + c];
  __syncthreads();
  float acc = b[c];
  #pragma unroll 8
  for (int k = 0; k < HD; ++k) acc = fmaf(pr[k], w[k * HD + c], acc);
  z1[g * HD + c] = acc;
}

__global__ __launch_bounds__(256) void bn1_k(float* __restrict__ z1, const float* __restrict__ g,
                                             const float* __restrict__ b){
  int c = threadIdx.x;
  float s = 0.f, q = 0.f;
  for (int r = 0; r < NGRAPH; ++r){
    float v = z1[r * HD + c];
    s += v; q += v * v;
  }
  float mean = s / (float)NGRAPH;
  float var  = fmaxf(q / (float)NGRAPH - mean * mean, 0.f);
  float inv  = rsqrtf(var + BN_EPS);
  float a = g[c] * inv, sh = b[c] - mean * a;
  for (int r = 0; r < NGRAPH; ++r)
    z1[r * HD + c] = fmaxf(z1[r * HD + c] * a + sh, 0.f);
}

__global__ __launch_bounds__(256) void lin2_k(const float* __restrict__ z1, const float* __restrict__ w,
                                              const float* __restrict__ b, float* __restrict__ out){
  __shared__ float zr[HD];
  int g = blockIdx.x;
  zr[threadIdx.x] = z1[g * HD + threadIdx.x];
  __syncthreads();
  if (threadIdx.x < NCLASS){
    float acc = b[threadIdx.x];
    #pragma unroll 8
    for (int k = 0; k < HD; ++k) acc = fmaf(zr[k], w[k * NCLASS + threadIdx.x], acc);
    out[g * NCLASS + threadIdx.x] = acc;
  }
}

// ---------------- host launch ----------------

extern "C" void kernel_launch(void* const* d_in, const int* in_sizes, int n_in,
                              void* d_out, int out_size, void* d_ws, size_t ws_size,
                              hipStream_t stream)
{
  const float* x      = (const float*)d_in[0];
  const int*   ei     = (const int*)d_in[1];
  const int*   batch  = (const int*)d_in[2];
  const float* W[3]   = {(const float*)d_in[3], (const float*)d_in[7], (const float*)d_in[11]};
  const float* gam[3] = {(const float*)d_in[5], (const float*)d_in[9], (const float*)d_in[13]};
  const float* bet[3] = {(const float*)d_in[6], (const float*)d_in[10], (const float*)d_in[14]};
  const float* lin1_w = (const float*)d_in[15];
  const float* lin1_b = (const float*)d_in[16];
  const float* bn1_g  = (const float*)d_in[17];
  const float* bn1_b  = (const float*)d_in[18];
  const float* lin2_w = (const float*)d_in[19];
  const float* lin2_b = (const float*)d_in[20];
  float* out = (float*)d_out;

  char* ws = (char*)d_ws;
  size_t off = 0;
  auto alloc = [&](size_t bytes) -> void* {
    void* p = ws + off;
    off = (off + bytes + 255) & ~(size_t)255;
    return p;
  };
  u16*   xb     = (u16*)alloc((size_t)N_NODES * HD * 2);     // 51.2 MB
  u16*   hn     = (u16*)alloc((size_t)N_NODES * HD * 2);     // 51.2 MB
  u16*   outb   = (u16*)alloc((size_t)N_NODES * HD * 2);     // 51.2 MB
  u16*   wt     = (u16*)alloc((size_t)3 * HD * HD * 2);
  int*   rowptr = (int*)alloc((size_t)(N_NODES + 1) * 4);
  int*   colx   = (int*)alloc((size_t)N_EDGES * 4);
  float* dis    = (float*)alloc((size_t)N_NODES * 4);
  float* prm    = (float*)alloc(2 * HD * 4);
  float* part   = (float*)alloc((size_t)1024 * 512 * 4);     // 2 MB
  int*   gs     = (int*)alloc(NGRAPH * 4);
  int*   ge     = (int*)alloc(NGRAPH * 4);
  float* pooled = (float*)alloc((size_t)NGRAPH * HD * 4);
  float* z1     = (float*)alloc((size_t)NGRAPH * HD * 4);
  (void)ws_size; (void)n_in; (void)in_sizes; (void)out_size;

  // build-phase scratch aliases outb (overwritten later by agg_k) and hn (written by gemm_k).
  int* esrc      = (int*)outb;                        // bytes [0, 12.8 MB)
  int* edst      = esrc + (size_t)N_EDGES;            // bytes [12.8, 25.6 MB)
  u32* blkcnt    = (u32*)(edst + (size_t)N_EDGES);    // bytes [25.6, 26.4 MB)
  u32* offs_p    = blkcnt + (size_t)NBLK * NBKT;      // bytes [26.4, 27.2 MB)  < 51.2 MB
  u32* total     = (u32*)hn;                          // 3.1 KB (read before gemm_k writes hn)
  u32* bkt_start = (u32*)hn + 1024;                   // 3.1 KB

  const int NB1 = (N_NODES + 255) / 256;            // 391

  cvt_k<<<12500, 256, 0, stream>>>(x, xb);
  wt3_k<<<768, 256, 0, stream>>>(W[0], W[1], W[2], wt);

  // CSR build: bucket counting-sort (no global atomics, locality-preserving writes)
  histA_k <<<NBLK, 256, 0, stream>>>(ei, blkcnt);
  scanB1_k<<<NBKT, 256, 0, stream>>>(blkcnt, offs_p, total);
  scanB2_k<<<1, 1024, 0, stream>>>(total, bkt_start);
  scatC_k <<<NBLK, 256, 0, stream>>>(ei, offs_p, bkt_start, esrc, edst);
  csrD_k  <<<NBKT, 128, 0, stream>>>(esrc, edst, bkt_start, rowptr, dis, colx);

  for (int l = 0; l < 3; ++l){
    const u16* gin = (l == 0) ? xb : outb;
    gemm_k<<<1563, 256, 0, stream>>>(gin, wt + (size_t)l * HD * HD, dis, prm, l > 0, hn);
    agg_k<<<12500, 256, 0, stream>>>(hn, rowptr, colx, dis, outb);
    stat1_k<<<1024, 256, 0, stream>>>(outb, part);
    stat2p_k<<<256, 256, 0, stream>>>(part, gam[l], bet[l], prm, 1024);
  }

  hipMemsetAsync(gs, 0x7f, NGRAPH * 4, stream);
  hipMemsetAsync(ge, 0, NGRAPH * 4, stream);
  bnd2_k<<<NB1, 256, 0, stream>>>(batch, gs, ge);
  pool_k<<<NGRAPH, 256, 0, stream>>>(outb, prm, gs, ge, pooled);
  lin1_k<<<NGRAPH, 256, 0, stream>>>(pooled, lin1_w, lin1_b, z1);
  bn1_k<<<1, 256, 0, stream>>>(z1, bn1_g, bn1_b);
  lin2_k<<<NGRAPH, 256, 0, stream>>>(z1, lin2_w, lin2_b, out);
}